// Round 4
// baseline (73.724 us; speedup 1.0000x reference)
//
#include <hip/hip_runtime.h>
#include <math.h>

#define SO3_EPS 1e-8f

typedef float f4 __attribute__((ext_vector_type(4)));

// Fused kernel: per-block Rodrigues (wave-uniform scalar work, hidden under
// memory latency) + streaming transform.
//
// pcd layout (B,H,3,P) fp32. Grid: x = P4 / (256*4), y = B*H.
// Each thread handles 4 float4 slots of each of the 3 channels
// (192 B in, 192 B out per thread) for deeper memory-level parallelism.
__global__ void __launch_bounds__(256)
vt_fused(const f4* __restrict__ pcd,
         const float* __restrict__ log_R,
         const float* __restrict__ shift,
         const float* __restrict__ scales,
         f4* __restrict__ out,
         int P4, int Hmask) {
    const int bh = blockIdx.y;          // wave-uniform
    const int h  = bh & Hmask;          // H is a power of two (16)

    // --- Rodrigues: R = I + fac1*K + fac2*K^2 (uniform per block) ---
    const float x = log_R[h * 3 + 0];
    const float y = log_R[h * 3 + 1];
    const float z = log_R[h * 3 + 2];

    const float theta2 = x * x + y * y + z * z;
    const float t2c    = fmaxf(theta2, SO3_EPS);
    const float theta  = sqrtf(t2c);
    const float fac1   = sinf(theta) / theta;
    const float fac2   = (1.0f - cosf(theta)) / t2c;

    const float sc0 = scales[h * 3 + 0], sc1 = scales[h * 3 + 1], sc2 = scales[h * 3 + 2];
    const float sh0 = shift[h * 3 + 0],  sh1 = shift[h * 3 + 1],  sh2 = shift[h * 3 + 2];

    // Rs[c][n] = R[c][n] * scales[n]
    const float m00 = (1.0f - fac2 * (y * y + z * z)) * sc0;
    const float m01 = (-fac1 * z + fac2 * x * y) * sc1;
    const float m02 = ( fac1 * y + fac2 * x * z) * sc2;
    const float m10 = ( fac1 * z + fac2 * x * y) * sc0;
    const float m11 = (1.0f - fac2 * (x * x + z * z)) * sc1;
    const float m12 = (-fac1 * x + fac2 * y * z) * sc2;
    const float m20 = (-fac1 * y + fac2 * x * z) * sc0;
    const float m21 = ( fac1 * x + fac2 * y * z) * sc1;
    const float m22 = (1.0f - fac2 * (x * x + y * y)) * sc2;

    // bias[n] = sum_c shift[c] * Rs[c][n]
    const float b0 = sh0 * m00 + sh1 * m10 + sh2 * m20;
    const float b1 = sh0 * m01 + sh1 * m11 + sh2 * m21;
    const float b2 = sh0 * m02 + sh1 * m12 + sh2 * m22;

    // --- streaming transform (32-bit indexing: buffer < 2^31 bytes) ---
    const int base = bh * 3 * P4;                        // float4 element index
    const int p4   = blockIdx.x * 1024 + threadIdx.x;    // 4 chunks, 256 apart

    const f4* __restrict__ src = pcd + base;
    f4* __restrict__       dst = out + base;

    f4 a[4], bb[4], c[4];
    #pragma unroll
    for (int k = 0; k < 4; ++k) a[k]  = __builtin_nontemporal_load(&src[p4 + k * 256]);
    #pragma unroll
    for (int k = 0; k < 4; ++k) bb[k] = __builtin_nontemporal_load(&src[p4 + P4 + k * 256]);
    #pragma unroll
    for (int k = 0; k < 4; ++k) c[k]  = __builtin_nontemporal_load(&src[p4 + 2 * P4 + k * 256]);

    #pragma unroll
    for (int k = 0; k < 4; ++k) {
        const f4 o0 = a[k] * m00 + bb[k] * m10 + c[k] * m20 + b0;
        __builtin_nontemporal_store(o0, &dst[p4 + k * 256]);
    }
    #pragma unroll
    for (int k = 0; k < 4; ++k) {
        const f4 o1 = a[k] * m01 + bb[k] * m11 + c[k] * m21 + b1;
        __builtin_nontemporal_store(o1, &dst[p4 + P4 + k * 256]);
    }
    #pragma unroll
    for (int k = 0; k < 4; ++k) {
        const f4 o2 = a[k] * m02 + bb[k] * m12 + c[k] * m22 + b2;
        __builtin_nontemporal_store(o2, &dst[p4 + 2 * P4 + k * 256]);
    }
}

extern "C" void kernel_launch(void* const* d_in, const int* in_sizes, int n_in,
                              void* d_out, int out_size, void* d_ws, size_t ws_size,
                              hipStream_t stream) {
    const f4*    pcd    = (const f4*)d_in[0];     // (B,H,3,P) fp32
    const float* log_R  = (const float*)d_in[1];  // (H,3)
    const float* shift  = (const float*)d_in[2];  // (H,3)
    const float* scales = (const float*)d_in[3];  // (H,3)
    f4* out = (f4*)d_out;

    const int H = in_sizes[1] / 3;                     // 16
    const long total = (long)in_sizes[0];              // B*H*3*P
    const int P = 131072;                              // fixed by problem
    const int BH = (int)(total / (3L * P));            // 128
    const int P4 = P / 4;                              // 32768

    dim3 grid(P4 / 1024, BH);                          // (32, 128)
    vt_fused<<<grid, 256, 0, stream>>>(pcd, log_R, shift, scales, out, P4, H - 1);
}

// Round 5
// 68.165 us; speedup vs baseline: 1.0816x; 1.0816x over previous
//
#include <hip/hip_runtime.h>
#include <math.h>

#define SO3_EPS 1e-8f

typedef float f4 __attribute__((ext_vector_type(4)));

// Fused kernel: per-block Rodrigues (wave-uniform scalar work, hidden under
// memory latency) + streaming transform.
//
// pcd layout (B,H,3,P) fp32. Grid: x = P4 / (256*2), y = B*H.
// Each thread handles 2 float4 slots of each of the 3 channels (96 B in, 96 B out).
// NOTE (round 4 post-mortem): 4 slots/thread REGRESSED (73.7 vs 68.0 us) —
// fewer blocks + 12 live float4s/thread lowered TLP. 2 slots is the sweet spot.
__global__ void __launch_bounds__(256)
vt_fused(const f4* __restrict__ pcd,
         const float* __restrict__ log_R,
         const float* __restrict__ shift,
         const float* __restrict__ scales,
         f4* __restrict__ out,
         int P4, int Hmask) {
    const int bh = blockIdx.y;          // wave-uniform
    const int h  = bh & Hmask;          // H is a power of two (16)

    // --- Rodrigues: R = I + fac1*K + fac2*K^2 (uniform per block) ---
    const float x = log_R[h * 3 + 0];
    const float y = log_R[h * 3 + 1];
    const float z = log_R[h * 3 + 2];

    const float theta2 = x * x + y * y + z * z;
    const float t2c    = fmaxf(theta2, SO3_EPS);
    const float theta  = sqrtf(t2c);
    const float fac1   = sinf(theta) / theta;
    const float fac2   = (1.0f - cosf(theta)) / t2c;

    const float sc0 = scales[h * 3 + 0], sc1 = scales[h * 3 + 1], sc2 = scales[h * 3 + 2];
    const float sh0 = shift[h * 3 + 0],  sh1 = shift[h * 3 + 1],  sh2 = shift[h * 3 + 2];

    // Rs[c][n] = R[c][n] * scales[n]
    const float m00 = (1.0f - fac2 * (y * y + z * z)) * sc0;
    const float m01 = (-fac1 * z + fac2 * x * y) * sc1;
    const float m02 = ( fac1 * y + fac2 * x * z) * sc2;
    const float m10 = ( fac1 * z + fac2 * x * y) * sc0;
    const float m11 = (1.0f - fac2 * (x * x + z * z)) * sc1;
    const float m12 = (-fac1 * x + fac2 * y * z) * sc2;
    const float m20 = (-fac1 * y + fac2 * x * z) * sc0;
    const float m21 = ( fac1 * x + fac2 * y * z) * sc1;
    const float m22 = (1.0f - fac2 * (x * x + y * y)) * sc2;

    // bias[n] = sum_c shift[c] * Rs[c][n]
    const float b0 = sh0 * m00 + sh1 * m10 + sh2 * m20;
    const float b1 = sh0 * m01 + sh1 * m11 + sh2 * m21;
    const float b2 = sh0 * m02 + sh1 * m12 + sh2 * m22;

    // --- streaming transform (32-bit indexing: buffer < 2^31 bytes) ---
    const int base = bh * 3 * P4;                        // float4 element index
    const int p4   = blockIdx.x * 512 + threadIdx.x;     // 2 chunks, 256 apart

    const f4* __restrict__ src = pcd + base;
    f4* __restrict__       dst = out + base;

    const f4 a0  = __builtin_nontemporal_load(&src[p4]);
    const f4 a1  = __builtin_nontemporal_load(&src[p4 + 256]);
    const f4 bb0 = __builtin_nontemporal_load(&src[p4 + P4]);
    const f4 bb1 = __builtin_nontemporal_load(&src[p4 + P4 + 256]);
    const f4 c0  = __builtin_nontemporal_load(&src[p4 + 2 * P4]);
    const f4 c1  = __builtin_nontemporal_load(&src[p4 + 2 * P4 + 256]);

    const f4 o00 = a0 * m00 + bb0 * m10 + c0 * m20 + b0;
    const f4 o01 = a1 * m00 + bb1 * m10 + c1 * m20 + b0;
    const f4 o10 = a0 * m01 + bb0 * m11 + c0 * m21 + b1;
    const f4 o11 = a1 * m01 + bb1 * m11 + c1 * m21 + b1;
    const f4 o20 = a0 * m02 + bb0 * m12 + c0 * m22 + b2;
    const f4 o21 = a1 * m02 + bb1 * m12 + c1 * m22 + b2;

    __builtin_nontemporal_store(o00, &dst[p4]);
    __builtin_nontemporal_store(o01, &dst[p4 + 256]);
    __builtin_nontemporal_store(o10, &dst[p4 + P4]);
    __builtin_nontemporal_store(o11, &dst[p4 + P4 + 256]);
    __builtin_nontemporal_store(o20, &dst[p4 + 2 * P4]);
    __builtin_nontemporal_store(o21, &dst[p4 + 2 * P4 + 256]);
}

extern "C" void kernel_launch(void* const* d_in, const int* in_sizes, int n_in,
                              void* d_out, int out_size, void* d_ws, size_t ws_size,
                              hipStream_t stream) {
    const f4*    pcd    = (const f4*)d_in[0];     // (B,H,3,P) fp32
    const float* log_R  = (const float*)d_in[1];  // (H,3)
    const float* shift  = (const float*)d_in[2];  // (H,3)
    const float* scales = (const float*)d_in[3];  // (H,3)
    f4* out = (f4*)d_out;

    const int H = in_sizes[1] / 3;                     // 16
    const long total = (long)in_sizes[0];              // B*H*3*P
    const int P = 131072;                              // fixed by problem
    const int BH = (int)(total / (3L * P));            // 128
    const int P4 = P / 4;                              // 32768

    dim3 grid(P4 / 512, BH);                           // (64, 128)
    vt_fused<<<grid, 256, 0, stream>>>(pcd, log_R, shift, scales, out, P4, H - 1);
}